// Round 14
// baseline (46.127 us; speedup 1.0000x reference)
//
#include <hip/hip_runtime.h>

#define NPIX    76800      // 240*320
#define WIDTH   320
#define NS      9
#define NTOT    (NPIX*NS)  // 691200
#define VDIM    320
#define NVOX    (VDIM*VDIM*VDIM)

// 256 threads/block, 2 items/thread -> block covers 512 consecutive outputs
#define BLOCK   256
#define ITEMS   512
#define NBLK    (NTOT / ITEMS)          // 1350
#define NXCD    8
#define SWZ_Q   (NBLK / NXCD)           // 168
#define SWZ_R   (NBLK % NXCD)           // 6

// output offsets (all float32 elements, concatenated in return order)
#define OFF_FV  0
#define OFF_FW  691200
#define OFF_RP  1382400
#define OFF_D   3456000
#define OFF_I   3532800
#define OFF_W8  20121600
#define OFF_C   25651200

typedef float f32x4 __attribute__((ext_vector_type(4)));
typedef float f32x2 __attribute__((ext_vector_type(2)));

__global__ __launch_bounds__(BLOCK, 4) void extractor_kernel(
    const float* __restrict__ depth,
    const float* __restrict__ extr,      // 4x4 row-major
    const float* __restrict__ intr,      // 3x3 row-major
    const float* __restrict__ vol,       // 320^3
    const float* __restrict__ wvol,      // 320^3
    const float* __restrict__ origin,    // 3
    const float* __restrict__ resolution,// 1
    float* __restrict__ out)
{
    __shared__ f32x4 lds4[BLOCK * 6];    // 24 KiB; each wave owns a 384-float4 slice

    // ---- bijective chunked XCD swizzle (1350 = 8*168 + 6) ----
    const int bid  = blockIdx.x;
    const int xcd  = bid & (NXCD - 1);
    const int base = bid >> 3;
    const int swz  = (xcd < SWZ_R ? xcd * (SWZ_Q + 1)
                                  : SWZ_R * (SWZ_Q + 1) + (xcd - SWZ_R) * SWZ_Q) + base;

    const int t   = threadIdx.x;
    const int gB  = swz * ITEMS;         // block's base output index

    // --- uniform preamble: inverse intrinsics, eye, origin (scalar) ---
    const float a00=intr[0], a01=intr[1], a02=intr[2];
    const float a10=intr[3], a11=intr[4], a12=intr[5];
    const float a20=intr[6], a21=intr[7], a22=intr[8];
    const float det = a00*(a11*a22 - a12*a21)
                    - a01*(a10*a22 - a12*a20)
                    + a02*(a10*a21 - a11*a20);
    const float id = 1.0f / det;
    const float i00 = (a11*a22 - a12*a21)*id;
    const float i01 = (a02*a21 - a01*a22)*id;
    const float i02 = (a01*a12 - a02*a11)*id;
    const float i10 = (a12*a20 - a10*a22)*id;
    const float i11 = (a00*a22 - a02*a20)*id;
    const float i12 = (a02*a10 - a00*a12)*id;
    const float i20 = (a10*a21 - a11*a20)*id;
    const float i21 = (a01*a20 - a00*a21)*id;
    const float i22 = (a00*a11 - a01*a10)*id;

    const float ox = origin[0], oy = origin[1], oz = origin[2];
    const float res = resolution[0];
    const float evx = (extr[3]  - ox) / res;
    const float evy = (extr[7]  - oy) / res;
    const float evz = (extr[11] - oz) / res;

    // --- per-item state (arrays fully unrolled -> static indices) ---
    int   tid_[2], p_[2], s_[2];
    float z_[2], cw_[2][3], pt_[2][3];
    int   pbase_[2][4], poff_[2][4], sel0_[2], sel1_[2];
    float wxy_[2][4], wz0_[2], wz1_[2];
    bool  vxy_[2][4], vz0_[2], vz1_[2];
    float inds_[2][24];
    f32x2 v2_[2][4], wv2_[2][4];

    #pragma unroll
    for (int it = 0; it < 2; ++it) {
        const int tid = gB + it*BLOCK + t;
        tid_[it] = tid;
        const int p = tid / 9;
        const int s = tid - p * 9;
        p_[it] = p; s_[it] = s;
        const int row = p / WIDTH;
        const int col = p - row * WIDTH;

        const float z = depth[p];
        z_[it] = z;

        const float up = (float)col * z;
        const float vp = (float)row * z;
        const float pcx = i00*up + i01*vp + i02*z;
        const float pcy = i10*up + i11*vp + i12*z;
        const float pcz = i20*up + i21*vp + i22*z;

        const float cwx = extr[0]*pcx + extr[1]*pcy + extr[2]*pcz  + extr[3];
        const float cwy = extr[4]*pcx + extr[5]*pcy + extr[6]*pcz  + extr[7];
        const float cwz = extr[8]*pcx + extr[9]*pcy + extr[10]*pcz + extr[11];
        cw_[it][0]=cwx; cw_[it][1]=cwy; cw_[it][2]=cwz;

        const float cvx = (cwx - ox) / res;
        const float cvy = (cwy - oy) / res;
        const float cvz = (cwz - oz) / res;

        float dx = cvx - evx, dy = cvy - evy, dz = cvz - evz;
        const float nrm = sqrtf(dx*dx + dy*dy + dz*dz);
        const float dn  = fmaxf(nrm, 1e-12f);
        dx /= dn; dy /= dn; dz /= dn;

        const float offs = (float)(s - 4);
        const float pt[3] = { cvx + offs*dx, cvy + offs*dy, cvz + offs*dz };
        pt_[it][0]=pt[0]; pt_[it][1]=pt[1]; pt_[it][2]=pt[2];

        float alpha[3], nb[3], fidx[3];
        #pragma unroll
        for (int k = 0; k < 3; ++k) {
            const float f  = floorf(pt[k]);
            const float c  = f + 0.5f;
            const float df = c - pt[k];
            nb[k]    = (df > 0.0f) ? 1.0f : ((df < 0.0f) ? -1.0f : 0.0f);
            alpha[k] = fabsf(pt[k] - c);
            fidx[k]  = f;
        }

        const float fz0 = fidx[2];
        const float fz1 = fidx[2] + nb[2];
        vz0_[it] = (fz0 >= 0.0f) && (fz0 < (float)VDIM);
        vz1_[it] = (fz1 >= 0.0f) && (fz1 < (float)VDIM);
        const int iz0 = (int)fminf(fmaxf(fz0, 0.0f), (float)(VDIM - 1));
        const int iz1 = (int)fminf(fmaxf(fz1, 0.0f), (float)(VDIM - 1));
        const int lo  = min(iz0, iz1);
        sel0_[it] = iz0 - lo;
        sel1_[it] = iz1 - lo;
        wz0_[it]  = 1.0f - alpha[2];
        wz1_[it]  = alpha[2];

        #pragma unroll
        for (int q4 = 0; q4 < 4; ++q4) {
            const float bx = (q4 >> 1) ? 1.0f : 0.0f;
            const float by = (q4 & 1)  ? 1.0f : 0.0f;
            const float fx = fidx[0] + bx * nb[0];
            const float fy = fidx[1] + by * nb[1];
            const bool  vx = (fx >= 0.0f) && (fx < (float)VDIM);
            const bool  vy = (fy >= 0.0f) && (fy < (float)VDIM);
            const int   ix = (int)fminf(fmaxf(fx, 0.0f), (float)(VDIM - 1));
            const int   iy = (int)fminf(fmaxf(fy, 0.0f), (float)(VDIM - 1));
            const float wx = (bx > 0.0f) ? alpha[0] : (1.0f - alpha[0]);
            const float wy = (by > 0.0f) ? alpha[1] : (1.0f - alpha[1]);
            const int   b  = (ix * VDIM + iy) * VDIM;
            pbase_[it][q4] = b + lo;
            poff_[it][q4]  = (b + lo == NVOX - 1) ? 1 : 0;
            wxy_[it][q4]   = wx * wy;
            vxy_[it][q4]   = vx && vy;
            inds_[it][(2*q4)*3 + 0]   = (float)ix;
            inds_[it][(2*q4)*3 + 1]   = (float)iy;
            inds_[it][(2*q4)*3 + 2]   = (float)iz0;
            inds_[it][(2*q4+1)*3 + 0] = (float)ix;
            inds_[it][(2*q4+1)*3 + 1] = (float)iy;
            inds_[it][(2*q4+1)*3 + 2] = (float)iz1;
        }

        // issue this item's 8 paired gathers immediately (stay in flight)
        #pragma unroll
        for (int q4 = 0; q4 < 4; ++q4)
            v2_[it][q4]  = *reinterpret_cast<const f32x2*>(vol  + pbase_[it][q4] - poff_[it][q4]);
        #pragma unroll
        for (int q4 = 0; q4 < 4; ++q4)
            wv2_[it][q4] = *reinterpret_cast<const f32x2*>(wvol + pbase_[it][q4] - poff_[it][q4]);
    }

    // --- gather-independent direct stores (both items) ---
    #pragma unroll
    for (int it = 0; it < 2; ++it) {
        const int tid = tid_[it];
        out[OFF_RP + tid*3 + 0] = pt_[it][0];
        out[OFF_RP + tid*3 + 1] = pt_[it][1];
        out[OFF_RP + tid*3 + 2] = pt_[it][2];
        if (s_[it] == 0) {
            const int p = p_[it];
            out[OFF_D + p] = z_[it];
            out[OFF_C + p*3 + 0] = cw_[it][0];
            out[OFF_C + p*3 + 1] = cw_[it][1];
            out[OFF_C + p*3 + 2] = cw_[it][2];
        }
    }

    // ---- wave-local LDS transposes (R10 mapping), slice reused 4x with fences
    const int w = t >> 6;
    const int l = t & 63;
    f32x4* wlds = lds4 + w * 384;        // wave-private 6 KiB slice

    #pragma unroll
    for (int it = 0; it < 2; ++it) {
        // inds: write l*6+c, read k*64+l  (slot m -> lane m/6, comp m%6)
        #pragma unroll
        for (int c = 0; c < 6; ++c) {
            f32x4 v4 = { inds_[it][c*4+0], inds_[it][c*4+1], inds_[it][c*4+2], inds_[it][c*4+3] };
            wlds[l*6 + c] = v4;
        }
        __builtin_amdgcn_sched_barrier(0);
        f32x4* outI = reinterpret_cast<f32x4*>(out + OFF_I) + (gB + it*BLOCK)*6 + w*384;
        #pragma unroll
        for (int k = 0; k < 6; ++k)
            __builtin_nontemporal_store(wlds[k*64 + l], outI + k*64 + l);
        __builtin_amdgcn_sched_barrier(0);

        // w8: write l*2+c, read {l, 64+l}
        {
            const float q0 = wxy_[it][0]*wz0_[it], q1 = wxy_[it][0]*wz1_[it];
            const float q2 = wxy_[it][1]*wz0_[it], q3 = wxy_[it][1]*wz1_[it];
            const float q4 = wxy_[it][2]*wz0_[it], q5 = wxy_[it][2]*wz1_[it];
            const float q6 = wxy_[it][3]*wz0_[it], q7 = wxy_[it][3]*wz1_[it];
            f32x4 w0 = { q0, q1, q2, q3 };
            f32x4 w1 = { q4, q5, q6, q7 };
            wlds[l*2 + 0] = w0;
            wlds[l*2 + 1] = w1;
        }
        __builtin_amdgcn_sched_barrier(0);
        f32x4* outW = reinterpret_cast<f32x4*>(out + OFF_W8) + (gB + it*BLOCK)*2 + w*128;
        __builtin_nontemporal_store(wlds[l],      outW + l);
        __builtin_nontemporal_store(wlds[64 + l], outW + 64 + l);
        __builtin_amdgcn_sched_barrier(0);
    }

    // --- consume gathers (item0 first -> its regs free before item1's wait) ---
    #pragma unroll
    for (int it = 0; it < 2; ++it) {
        float fv = 0.0f, fw = 0.0f;
        #pragma unroll
        for (int q4 = 0; q4 < 4; ++q4) {
            const float wz0e = (vxy_[it][q4] && vz0_[it]) ? wxy_[it][q4] * wz0_[it] : 0.0f;
            const float wz1e = (vxy_[it][q4] && vz1_[it]) ? wxy_[it][q4] * wz1_[it] : 0.0f;
            const int   e0 = sel0_[it] + poff_[it][q4];
            const int   e1 = sel1_[it] + poff_[it][q4];
            fv += v2_[it][q4][e0]  * wz0e + v2_[it][q4][e1]  * wz1e;
            fw += wv2_[it][q4][e0] * wz0e + wv2_[it][q4][e1] * wz1e;
        }
        __builtin_nontemporal_store(fv, out + OFF_FV + tid_[it]);
        __builtin_nontemporal_store(fw, out + OFF_FW + tid_[it]);
    }
}

extern "C" void kernel_launch(void* const* d_in, const int* in_sizes, int n_in,
                              void* d_out, int out_size, void* d_ws, size_t ws_size,
                              hipStream_t stream) {
    const float* depth      = (const float*)d_in[0];
    const float* extr       = (const float*)d_in[1];
    const float* intr       = (const float*)d_in[2];
    const float* vol        = (const float*)d_in[3];
    const float* wvol       = (const float*)d_in[4];
    const float* origin     = (const float*)d_in[5];
    const float* resolution = (const float*)d_in[6];
    float* out = (float*)d_out;

    extractor_kernel<<<NBLK, BLOCK, 0, stream>>>(
        depth, extr, intr, vol, wvol, origin, resolution, out);
}

// Round 15
// 42.421 us; speedup vs baseline: 1.0874x; 1.0874x over previous
//
#include <hip/hip_runtime.h>

#define NPIX    76800      // 240*320
#define WIDTH   320
#define NS      9
#define NTOT    (NPIX*NS)  // 691200
#define VDIM    320
#define NVOX    (VDIM*VDIM*VDIM)

// launch: identity mapping (tid = g), 256 threads/block, 2700 blocks
#define BLOCK   256
#define NBLK    (NTOT / BLOCK)          // 2700
#define NXCD    8
#define SWZ_Q   (NBLK / NXCD)           // 337
#define SWZ_R   (NBLK % NXCD)           // 4

// output offsets (all float32 elements, concatenated in return order)
#define OFF_FV  0
#define OFF_FW  691200
#define OFF_RP  1382400
#define OFF_D   3456000
#define OFF_I   3532800
#define OFF_W8  20121600
#define OFF_C   25651200

typedef float f32x4 __attribute__((ext_vector_type(4)));
typedef float f32x2 __attribute__((ext_vector_type(2)));

__global__ __launch_bounds__(BLOCK, 6) void extractor_kernel(
    const float* __restrict__ depth,
    const float* __restrict__ extr,      // 4x4 row-major
    const float* __restrict__ intr,      // 3x3 row-major
    const float* __restrict__ vol,       // 320^3
    const float* __restrict__ wvol,      // 320^3
    const float* __restrict__ origin,    // 3
    const float* __restrict__ resolution,// 1
    float* __restrict__ out)
{
    __shared__ f32x4 lds4[BLOCK * 6];    // 24 KiB; each wave owns a 384-float4 slice

    // ---- bijective chunked XCD swizzle (2700 = 8*337 + 4) ----
    const int bid  = blockIdx.x;
    const int xcd  = bid & (NXCD - 1);
    const int base = bid >> 3;
    const int swz  = (xcd < SWZ_R ? xcd * (SWZ_Q + 1)
                                  : SWZ_R * (SWZ_Q + 1) + (xcd - SWZ_R) * SWZ_Q) + base;

    const int t   = threadIdx.x;
    const int gB  = swz * BLOCK;         // block's base output index
    const int tid = gB + t;              // identity: output index == work index
    const int p   = tid / 9;             // pixel (row-major)
    const int s   = tid - p * 9;         // sample 0..8

    const int row = p / WIDTH;           // v
    const int col = p - row * WIDTH;     // u

    const float z = depth[p];

    // --- 3x3 inverse of intrinsics (adjugate; uniform values) ---
    const float a00=intr[0], a01=intr[1], a02=intr[2];
    const float a10=intr[3], a11=intr[4], a12=intr[5];
    const float a20=intr[6], a21=intr[7], a22=intr[8];
    const float det = a00*(a11*a22 - a12*a21)
                    - a01*(a10*a22 - a12*a20)
                    + a02*(a10*a21 - a11*a20);
    const float id = 1.0f / det;
    const float i00 = (a11*a22 - a12*a21)*id;
    const float i01 = (a02*a21 - a01*a22)*id;
    const float i02 = (a01*a12 - a02*a11)*id;
    const float i10 = (a12*a20 - a10*a22)*id;
    const float i11 = (a00*a22 - a02*a20)*id;
    const float i12 = (a02*a10 - a00*a12)*id;
    const float i20 = (a10*a21 - a11*a20)*id;
    const float i21 = (a01*a20 - a00*a21)*id;
    const float i22 = (a00*a11 - a01*a10)*id;

    // pts_p = (u*z, v*z, z)
    const float up = (float)col * z;
    const float vp = (float)row * z;
    const float pcx = i00*up + i01*vp + i02*z;
    const float pcy = i10*up + i11*vp + i12*z;
    const float pcz = i20*up + i21*vp + i22*z;

    // world coords = (E @ [pc,1])[:3]
    const float cwx = extr[0]*pcx + extr[1]*pcy + extr[2]*pcz  + extr[3];
    const float cwy = extr[4]*pcx + extr[5]*pcy + extr[6]*pcz  + extr[7];
    const float cwz = extr[8]*pcx + extr[9]*pcy + extr[10]*pcz + extr[11];

    const float ox = origin[0], oy = origin[1], oz = origin[2];
    const float res = resolution[0];

    // voxel coords
    const float cvx = (cwx - ox) / res;
    const float cvy = (cwy - oy) / res;
    const float cvz = (cwz - oz) / res;
    const float evx = (extr[3]  - ox) / res;
    const float evy = (extr[7]  - oy) / res;
    const float evz = (extr[11] - oz) / res;

    float dx = cvx - evx, dy = cvy - evy, dz = cvz - evz;
    const float nrm = sqrtf(dx*dx + dy*dy + dz*dz);
    const float dn  = fmaxf(nrm, 1e-12f);
    dx /= dn; dy /= dn; dz /= dn;

    const float offs = (float)(s - 4);   // offs in [-4,4]
    const float pt[3] = { cvx + offs*dx, cvy + offs*dy, cvz + offs*dz };

    // --- trilinear setup ---
    float alpha[3], nb[3], fidx[3];
    #pragma unroll
    for (int k = 0; k < 3; ++k) {
        const float f  = floorf(pt[k]);
        const float c  = f + 0.5f;
        const float df = c - pt[k];
        nb[k]    = (df > 0.0f) ? 1.0f : ((df < 0.0f) ? -1.0f : 0.0f);
        alpha[k] = fabsf(pt[k] - c);
        fidx[k]  = f;
    }

    // z corner indexes are shared by all 4 (x,y) pairs
    const float fz0 = fidx[2];
    const float fz1 = fidx[2] + nb[2];
    const bool  vz0 = (fz0 >= 0.0f) && (fz0 < (float)VDIM);
    const bool  vz1 = (fz1 >= 0.0f) && (fz1 < (float)VDIM);
    const int   iz0 = (int)fminf(fmaxf(fz0, 0.0f), (float)(VDIM - 1));
    const int   iz1 = (int)fminf(fmaxf(fz1, 0.0f), (float)(VDIM - 1));
    const int   lo  = min(iz0, iz1);
    const int   sel0 = iz0 - lo;         // 0 or 1
    const int   sel1 = iz1 - lo;
    const float az   = alpha[2];
    const float wz0  = 1.0f - az, wz1 = az;

    // phase 1: 4 pair-addresses + weights + validity
    int   pbase[4];
    int   poff[4];                       // unaligned-guard shift (0 or 1)
    float wxy[4];
    bool  vxy[4];
    float indsbuf[24];
    #pragma unroll
    for (int q4 = 0; q4 < 4; ++q4) {
        const float bx = (q4 >> 1) ? 1.0f : 0.0f;
        const float by = (q4 & 1)  ? 1.0f : 0.0f;
        const float fx = fidx[0] + bx * nb[0];
        const float fy = fidx[1] + by * nb[1];
        const bool  vx = (fx >= 0.0f) && (fx < (float)VDIM);
        const bool  vy = (fy >= 0.0f) && (fy < (float)VDIM);
        const int   ix = (int)fminf(fmaxf(fx, 0.0f), (float)(VDIM - 1));
        const int   iy = (int)fminf(fmaxf(fy, 0.0f), (float)(VDIM - 1));
        const float wx = (bx > 0.0f) ? alpha[0] : (1.0f - alpha[0]);
        const float wy = (by > 0.0f) ? alpha[1] : (1.0f - alpha[1]);
        const int   b  = (ix * VDIM + iy) * VDIM;
        pbase[q4] = b;
        poff[q4]  = (b + lo == NVOX - 1) ? 1 : 0;   // only possible when sel0==sel1==0
        wxy[q4]   = wx * wy;
        vxy[q4]   = vx && vy;
        // inds: corners 2*q4 (z-bit 0) and 2*q4+1 (z-bit 1)
        indsbuf[(2*q4)*3 + 0]   = (float)ix;
        indsbuf[(2*q4)*3 + 1]   = (float)iy;
        indsbuf[(2*q4)*3 + 2]   = (float)iz0;
        indsbuf[(2*q4+1)*3 + 0] = (float)ix;
        indsbuf[(2*q4+1)*3 + 1] = (float)iy;
        indsbuf[(2*q4+1)*3 + 2] = (float)iz1;
    }

    // phase 2: 8 paired gathers (dwordx2), all issued back-to-back;
    // no barrier anywhere -> these stay in flight until the final consume
    f32x2 v2[4], wv2[4];
    #pragma unroll
    for (int q4 = 0; q4 < 4; ++q4)
        v2[q4]  = *reinterpret_cast<const f32x2*>(vol  + pbase[q4] + lo - poff[q4]);
    #pragma unroll
    for (int q4 = 0; q4 < 4; ++q4)
        wv2[q4] = *reinterpret_cast<const f32x2*>(wvol + pbase[q4] + lo - poff[q4]);

    // phase 3: gather-independent direct stores (small, partial-line -> keep cached)
    out[OFF_RP + tid*3 + 0] = pt[0];
    out[OFF_RP + tid*3 + 1] = pt[1];
    out[OFF_RP + tid*3 + 2] = pt[2];
    if (s == 0) {
        out[OFF_D + p] = z;
        out[OFF_C + p*3 + 0] = cwx;
        out[OFF_C + p*3 + 1] = cwy;
        out[OFF_C + p*3 + 2] = cwz;
    }

    // ---- wave-local LDS transpose: no __syncthreads (same-wave DS ops are
    // in-order in the LDS pipe); sched_barrier(0) fences forbid compiler
    // motion across the cross-lane write->read boundaries (rule #18).
    const int w = t >> 6;                // wave 0..3
    const int l = t & 63;                // lane
    f32x4* wlds = lds4 + w * 384;        // wave-private 6 KiB slice

    // phase 4: inds -> one-pass wave-local transpose (R10 mapping, verified):
    // write slot l*6+c, read slot k*64+l  (slot m holds lane m/6, comp m%6)
    #pragma unroll
    for (int c = 0; c < 6; ++c) {
        f32x4 v4 = { indsbuf[c*4+0], indsbuf[c*4+1], indsbuf[c*4+2], indsbuf[c*4+3] };
        wlds[l*6 + c] = v4;
    }
    __builtin_amdgcn_sched_barrier(0);   // writes ordered before reads
    f32x4* outI = reinterpret_cast<f32x4*>(out + OFF_I) + gB*6 + w*384;
    #pragma unroll
    for (int k = 0; k < 6; ++k)
        __builtin_nontemporal_store(wlds[k*64 + l], outI + k*64 + l);
    __builtin_amdgcn_sched_barrier(0);   // reads drained before slice reuse

    // phase 5: w8 -> wave-local transpose (reuse slice) -> coalesced NT stream
    // write slot l*2+c, read slots {l, 64+l} (slot m holds lane m/2, comp m%2)
    {
        const float w00 = wxy[0]*wz0, w01 = wxy[0]*wz1;
        const float w10 = wxy[1]*wz0, w11 = wxy[1]*wz1;
        const float w20 = wxy[2]*wz0, w21 = wxy[2]*wz1;
        const float w30 = wxy[3]*wz0, w31 = wxy[3]*wz1;
        f32x4 w0 = { w00, w01, w10, w11 };
        f32x4 w1 = { w20, w21, w30, w31 };
        wlds[l*2 + 0] = w0;
        wlds[l*2 + 1] = w1;
    }
    __builtin_amdgcn_sched_barrier(0);
    f32x4* outW = reinterpret_cast<f32x4*>(out + OFF_W8) + gB*2 + w*128;
    __builtin_nontemporal_store(wlds[l],      outW + l);
    __builtin_nontemporal_store(wlds[64 + l], outW + 64 + l);
    __builtin_amdgcn_sched_barrier(0);

    // phase 6: consume gathers (first and only vmcnt wait on them)
    float fv = 0.0f, fw = 0.0f;
    #pragma unroll
    for (int q4 = 0; q4 < 4; ++q4) {
        const float wz0e = (vxy[q4] && vz0) ? wxy[q4] * wz0 : 0.0f;
        const float wz1e = (vxy[q4] && vz1) ? wxy[q4] * wz1 : 0.0f;
        const int   e0 = sel0 + poff[q4];
        const int   e1 = sel1 + poff[q4];
        fv += v2[q4][e0]  * wz0e + v2[q4][e1]  * wz1e;
        fw += wv2[q4][e0] * wz0e + wv2[q4][e1] * wz1e;
    }
    __builtin_nontemporal_store(fv, out + OFF_FV + tid);
    __builtin_nontemporal_store(fw, out + OFF_FW + tid);
}

extern "C" void kernel_launch(void* const* d_in, const int* in_sizes, int n_in,
                              void* d_out, int out_size, void* d_ws, size_t ws_size,
                              hipStream_t stream) {
    const float* depth      = (const float*)d_in[0];
    const float* extr       = (const float*)d_in[1];
    const float* intr       = (const float*)d_in[2];
    const float* vol        = (const float*)d_in[3];
    const float* wvol       = (const float*)d_in[4];
    const float* origin     = (const float*)d_in[5];
    const float* resolution = (const float*)d_in[6];
    float* out = (float*)d_out;

    extractor_kernel<<<NBLK, BLOCK, 0, stream>>>(
        depth, extr, intr, vol, wvol, origin, resolution, out);
}